// Round 3
// baseline (525.599 us; speedup 1.0000x reference)
//
#include <hip/hip_runtime.h>

#define G 4
#define NBATCH 8
#define HIN 128
#define HD 2324
#define NW 36864
#define NO 36928   // NW + 64 biases
#define NO4 (NO / 4)        // 9232
#define GIN 64
#define GOUT 64
#define HIMG 64
#define WIMG 64
#define CIN 256
#define DSPLIT 16
#define DCHUNK 148          // 15*148 + 104 = 2324; all chunks %4==0
#define OSPLIT 4            // k3: 16 output channels per block

// K1: h_t[g][d][b] = relu(b1[g][d] + sum_i hyper[b][i] * W1[g][i][d])
// d-major layout so K2 reads 8 contiguous batch values per d.
__global__ __launch_bounds__(256) void k1_hyper_l1(
    const float* __restrict__ hyper, const float* __restrict__ W1,
    const float* __restrict__ b1, float* __restrict__ h_t) {
  int g = blockIdx.y;
  int d = blockIdx.x * 256 + threadIdx.x;
  if (d >= HD) return;
  const float* W1g = W1 + (size_t)g * HIN * HD + d;
  float bias = b1[g * HD + d];
  float acc[NBATCH];
#pragma unroll
  for (int b = 0; b < NBATCH; ++b) acc[b] = bias;
  for (int i = 0; i < HIN; ++i) {
    float wv = W1g[(size_t)i * HD];
#pragma unroll
    for (int b = 0; b < NBATCH; ++b)
      acc[b] = fmaf(hyper[b * HIN + i], wv, acc[b]);
  }
  float4* hp = (float4*)(h_t + ((size_t)g * HD + d) * 8);
  hp[0] = make_float4(fmaxf(acc[0], 0.f), fmaxf(acc[1], 0.f),
                      fmaxf(acc[2], 0.f), fmaxf(acc[3], 0.f));
  hp[1] = make_float4(fmaxf(acc[4], 0.f), fmaxf(acc[5], 0.f),
                      fmaxf(acc[6], 0.f), fmaxf(acc[7], 0.f));
}

// 32 FMAs for one d: h (uniform s_load) x W2 float4
#define FMA_D(wv, hoff)                                   \
  {                                                       \
    _Pragma("unroll")                                     \
    for (int b = 0; b < NBATCH; ++b) {                    \
      float hv = hh[(hoff) * 8 + b];                      \
      acc[b].x = fmaf(hv, (wv).x, acc[b].x);              \
      acc[b].y = fmaf(hv, (wv).y, acc[b].y);              \
      acc[b].z = fmaf(hv, (wv).z, acc[b].z);              \
      acc[b].w = fmaf(hv, (wv).w, acc[b].w);              \
    }                                                     \
  }

// K2: partial[ds][g][b][o] = sum_{d in chunk} h[g][b][d] * W2[g][d][o]
// float4 W2 stream, 4-deep software pipeline, split-K over 16 chunks.
__global__ __launch_bounds__(256) void k2_hyper_l2(
    const float* __restrict__ h_t, const float* __restrict__ W2,
    float* __restrict__ partial) {
  int g = blockIdx.y, ds = blockIdx.z;
  int o4 = blockIdx.x * 256 + threadIdx.x;
  bool active = (o4 < NO4);
  if (!active) o4 = NO4 - 1;               // clamp; mask at store
  const float4* W2g = (const float4*)(W2 + (size_t)g * HD * NO) + o4;
  const float* hg = h_t + (size_t)g * HD * 8;
  int d0 = ds * DCHUNK;
  int d1 = d0 + DCHUNK; if (d1 > HD) d1 = HD;
  int nd = d1 - d0;                        // multiple of 4, >= 4

  float4 acc[NBATCH];
#pragma unroll
  for (int b = 0; b < NBATCH; ++b) acc[b] = make_float4(0.f, 0.f, 0.f, 0.f);

  const size_t WS = NO4;
  const float4* Wp = W2g + (size_t)d0 * WS;
  float4 w0 = Wp[0], w1 = Wp[WS], w2 = Wp[2 * WS], w3 = Wp[3 * WS];
  int dd = 0;
  for (; dd < nd - 4; dd += 4) {
    const float4* Wn = Wp + (size_t)(dd + 4) * WS;
    float4 n0 = Wn[0], n1 = Wn[WS], n2 = Wn[2 * WS], n3 = Wn[3 * WS];
    const float* hh = hg + (size_t)(d0 + dd) * 8;   // 32 contiguous -> s_load x16
    FMA_D(w0, 0) FMA_D(w1, 1) FMA_D(w2, 2) FMA_D(w3, 3)
    w0 = n0; w1 = n1; w2 = n2; w3 = n3;
  }
  {
    const float* hh = hg + (size_t)(d0 + dd) * 8;
    FMA_D(w0, 0) FMA_D(w1, 1) FMA_D(w2, 2) FMA_D(w3, 3)
  }

  if (active) {
    float4* pout = (float4*)partial + (size_t)(ds * G * NBATCH + g * NBATCH) * NO4 + o4;
#pragma unroll
    for (int b = 0; b < NBATCH; ++b) pout[(size_t)b * NO4] = acc[b];
  }
}

// K2r: sum partials + b2; write weights TRANSPOSED to wt[g][b][c][o][9]
// (so K3's per-channel weight block is 144 contiguous floats) + bias_t[g][b][o].
__global__ __launch_bounds__(256) void k2_reduce(
    const float* __restrict__ partial, const float* __restrict__ b2,
    float* __restrict__ wt, float* __restrict__ bias_t) {
  const int NF4 = G * NBATCH * NO4;        // 295424
  int q = blockIdx.x * 256 + threadIdx.x;
  if (q >= NF4) return;
  int gb = q / NO4;                        // g*8+b
  int g = gb >> 3;
  int o4 = q - gb * NO4;
  float4 s = ((const float4*)(b2 + (size_t)g * NO))[o4];
  const float4* p = (const float4*)partial + q;
#pragma unroll
  for (int ds = 0; ds < DSPLIT; ++ds) {
    float4 v = p[(size_t)ds * NF4];
    s.x += v.x; s.y += v.y; s.z += v.z; s.w += v.w;
  }
  float v[4] = {s.x, s.y, s.z, s.w};
  int f0 = o4 * 4;
#pragma unroll
  for (int i = 0; i < 4; ++i) {
    int f = f0 + i;
    if (f < NW) {
      int o = f / 576;
      int ck = f - o * 576;                // c*9 + k
      int c = ck / 9, k = ck - c * 9;
      wt[(size_t)gb * NW + c * 576 + o * 9 + k] = v[i];
    } else {
      bias_t[gb * GOUT + (f - NW)] = v[i];
    }
  }
}

// K3: grouped dynamic 3x3 conv. block = (16x16 pixel tile, g, b*4+os);
// 16 output channels per block; image tile double-buffered in LDS;
// weights via contiguous scalar loads from transposed layout.
__global__ __launch_bounds__(256) void k3_conv(
    const float* __restrict__ image, const float* __restrict__ wt,
    const float* __restrict__ bias_t, float* __restrict__ out) {
  __shared__ float tile[2][18 * 18];
  int t = blockIdx.x;
  int g = blockIdx.y;
  int bz = blockIdx.z;
  int b = bz >> 2, os = bz & 3;
  int gb = g * NBATCH + b;
  int y0 = (t >> 2) << 4, x0 = (t & 3) << 4;
  int tid = threadIdx.x;
  int py = tid >> 4, px = tid & 15;
  int obase = os * 16;

  const float* wtb = wt + (size_t)gb * NW + obase * 9;
  const float* imgb = image + ((size_t)b * CIN + g * GIN) * (HIMG * WIMG);

  float acc[16];
#pragma unroll
  for (int oo = 0; oo < 16; ++oo) acc[oo] = bias_t[gb * GOUT + obase + oo];

  for (int i = tid; i < 18 * 18; i += 256) {
    int iy = i / 18, ix = i % 18;
    int gy = y0 - 1 + iy, gx = x0 - 1 + ix;
    float v = 0.0f;
    if (gy >= 0 && gy < HIMG && gx >= 0 && gx < WIMG) v = imgb[gy * WIMG + gx];
    tile[0][i] = v;
  }
  __syncthreads();

  for (int c = 0; c < GIN; ++c) {
    int cur = c & 1;
    if (c + 1 < GIN) {
      const float* imgc = imgb + (size_t)(c + 1) * (HIMG * WIMG);
      for (int i = tid; i < 18 * 18; i += 256) {
        int iy = i / 18, ix = i % 18;
        int gy = y0 - 1 + iy, gx = x0 - 1 + ix;
        float v = 0.0f;
        if (gy >= 0 && gy < HIMG && gx >= 0 && gx < WIMG) v = imgc[gy * WIMG + gx];
        tile[cur ^ 1][i] = v;
      }
    }
    float p[9];
#pragma unroll
    for (int ky = 0; ky < 3; ++ky)
#pragma unroll
      for (int kx = 0; kx < 3; ++kx)
        p[ky * 3 + kx] = tile[cur][(py + ky) * 18 + (px + kx)];
    const float* wc = wtb + c * 576;       // 144 contiguous floats for 16 o's
#pragma unroll
    for (int oo = 0; oo < 16; ++oo) {
      const float* w = wc + oo * 9;
#pragma unroll
      for (int k = 0; k < 9; ++k)
        acc[oo] = fmaf(p[k], w[k], acc[oo]);
    }
    __syncthreads();
  }

  int y = y0 + py, x = x0 + px;
  float* outp = out + ((size_t)b * CIN + g * GOUT + obase) * (HIMG * WIMG)
              + y * WIMG + x;
#pragma unroll
  for (int oo = 0; oo < 16; ++oo)
    outp[(size_t)oo * (HIMG * WIMG)] = acc[oo];
}

extern "C" void kernel_launch(void* const* d_in, const int* in_sizes, int n_in,
                              void* d_out, int out_size, void* d_ws, size_t ws_size,
                              hipStream_t stream) {
  const float* image = (const float*)d_in[0];
  const float* hyper = (const float*)d_in[1];
  const float* W1    = (const float*)d_in[2];
  const float* b1    = (const float*)d_in[3];
  const float* W2    = (const float*)d_in[4];
  const float* b2    = (const float*)d_in[5];
  float* out = (float*)d_out;

  float* h_t     = (float*)d_ws;                              // G*HD*8      = 74368
  float* wt      = h_t + (size_t)G * HD * 8;                  // G*B*NW      = 1179648
  float* bias_t  = wt + (size_t)G * NBATCH * NW;              // G*B*64      = 2048
  float* partial = bias_t + (size_t)G * NBATCH * GOUT;        // 16*32*NO4*4 = 18907136

  k1_hyper_l1<<<dim3((HD + 255) / 256, G), 256, 0, stream>>>(hyper, W1, b1, h_t);
  k2_hyper_l2<<<dim3((NO4 + 255) / 256, G, DSPLIT), 256, 0, stream>>>(h_t, W2, partial);
  k2_reduce<<<dim3((G * NBATCH * NO4 + 255) / 256), 256, 0, stream>>>(partial, b2, wt, bias_t);
  k3_conv<<<dim3(16, G, NBATCH * OSPLIT), 256, 0, stream>>>(image, wt, bias_t, out);
}